// Round 3
// baseline (919.788 us; speedup 1.0000x reference)
//
#include <hip/hip_runtime.h>
#include <math.h>

#define HD   64
#define EIN  8
#define MT   128          // edges per block
#define KP   160          // layer-1 K padded to 5*32
#define NORM_INV 0.01f

typedef short bf16x8 __attribute__((ext_vector_type(8)));
typedef float f32x4  __attribute__((ext_vector_type(4)));

// ws layout (bytes): hbf [N*64 ushort] at 0 ; w1t [64*160 ushort] ; w2t [64*72 ushort]
#define W1T_OFF(nf)  ((size_t)(nf) * HD * 2)          // nf = N*HD floats of h
#define WS_NEED(nf)  (W1T_OFF(nf) + 64*160*2 + 64*72*2)

__device__ __forceinline__ unsigned short f2bf(float f) {
    union { float f; unsigned u; } v; v.f = f;
    unsigned r = v.u + 0x7FFFu + ((v.u >> 16) & 1u);
    return (unsigned short)(r >> 16);
}
__device__ __forceinline__ float silu_f(float x) {
    return x * __builtin_amdgcn_rcpf(1.0f + __expf(-x));
}

// ---- prep: coord->out copy + h -> bf16 ----
__global__ void prep_h_kernel(const float* __restrict__ h, unsigned short* __restrict__ hbf,
                              int npairs, const float* __restrict__ coord,
                              float* __restrict__ out, int n3) {
    int i = blockIdx.x * blockDim.x + threadIdx.x;
    if (i < npairs) {
        float2 v = reinterpret_cast<const float2*>(h)[i];
        ushort2 o; o.x = f2bf(v.x); o.y = f2bf(v.y);
        reinterpret_cast<ushort2*>(hbf)[i] = o;
    }
    if (i < n3) out[i] = coord[i];
}

// ---- prep: transposed bf16 weights (B-fragment wants N-major, K-contiguous) ----
__global__ void prep_w_kernel(const float* __restrict__ W1, const float* __restrict__ W2,
                              unsigned short* __restrict__ w1t, unsigned short* __restrict__ w2t) {
    int t = threadIdx.x;
    for (int i = t; i < 64 * KP; i += 256) {
        int n = i / KP, k = i - n * KP;
        w1t[i] = (k < 136) ? f2bf(W1[k * HD + n]) : (unsigned short)0;
    }
    for (int i = t; i < 64 * 72; i += 256) {
        int n = i / 72, k = i - n * 72;
        w2t[i] = (k < 64) ? f2bf(W2[k * HD + n]) : (unsigned short)0;
    }
}

// ---- main MFMA kernel ----
// LDS map (71168 B): sA [128][160]u16 stride 320B at 0 (aliases X1 [128][72]u16
// stride 144B and X2 [128][66]f32 stride 264B); sW1 [64][160]u16 at 40960;
// sW2 [64][72]u16 at 61440; b1 f32[64] at 70656; b2 f32[64] at 70912.
__global__ __launch_bounds__(256, 2) void egnn_mfma_kernel(
    const unsigned short* __restrict__ hbf,
    const float* __restrict__ coord,
    const int*   __restrict__ eidx,
    const float* __restrict__ eattr,
    const unsigned short* __restrict__ w1t,
    const unsigned short* __restrict__ w2t,
    const float* __restrict__ b1,
    const float* __restrict__ b2,
    const float* __restrict__ W3,
    float* __restrict__ out,
    int E_)
{
    __shared__ char smem[71168];
    unsigned short* sA  = (unsigned short*)smem;
    unsigned short* sW1 = (unsigned short*)(smem + 40960);
    unsigned short* sW2 = (unsigned short*)(smem + 61440);
    float* sB1 = (float*)(smem + 70656);
    float* sB2 = (float*)(smem + 70912);

    const int t  = threadIdx.x;
    const int e0 = blockIdx.x * MT;

    // ---------- stage A tile (2 threads per edge; waves uniform on `part`) ----------
    {
        int el = t & (MT - 1), part = t >> 7;
        int e = e0 + el; if (e >= E_) e = E_ - 1;
        if (part == 0) {
            int r = eidx[e];
            const uint4* src = (const uint4*)(hbf + (size_t)r * HD);
            uint4* dst = (uint4*)(sA + el * KP);        // k = 0..63
#pragma unroll
            for (int i = 0; i < 8; ++i) dst[i] = src[i];
            uint4 z; z.x = z.y = z.z = z.w = 0;          // zero pad k = 144..159
            dst[18] = z; dst[19] = z;
        } else {
            int c = eidx[(size_t)E_ + e];
            const uint4* src = (const uint4*)(hbf + (size_t)c * HD);
            uint4* dst = (uint4*)(sA + el * KP + HD);    // k = 64..127
#pragma unroll
            for (int i = 0; i < 8; ++i) dst[i] = src[i];
            const float4* eap = (const float4*)(eattr + (size_t)e * EIN);
            float4 a0 = eap[0], a1 = eap[1];
            uint4 v;                                     // k = 128..135 at slot 16, 136..143 slot 17
            v.x = f2bf(a0.x) | ((unsigned)f2bf(a0.y) << 16);
            v.y = f2bf(a0.z) | ((unsigned)f2bf(a0.w) << 16);
            v.z = f2bf(a1.x) | ((unsigned)f2bf(a1.y) << 16);
            v.w = f2bf(a1.z) | ((unsigned)f2bf(a1.w) << 16);
            ((uint4*)(sA + el * KP))[16] = v;
            uint4 z; z.x = z.y = z.z = z.w = 0;          // zero k = 136..143
            ((uint4*)(sA + el * KP))[17] = z;
        }
    }
    // ---------- stage weights + biases ----------
    {
        const uint4* s1 = (const uint4*)w1t; uint4* d1 = (uint4*)sW1;
        for (int i = t; i < (64 * KP) / 8; i += 256) d1[i] = s1[i];
        const uint4* s2 = (const uint4*)w2t; uint4* d2 = (uint4*)sW2;
        for (int i = t; i < (64 * 72) / 8; i += 256) d2[i] = s2[i];
        if (t < 64) sB1[t] = b1[t];
        else if (t < 128) sB2[t - 64] = b2[t - 64];
    }
    __syncthreads();

    const int w = t >> 6, lane = t & 63;
    const int m = lane & 15, q = lane >> 4;
    const int rowb = 32 * w;                 // this wave owns edge-rows rowb..rowb+31

    // ---------- layer 1: [128,160] @ [160,64] ----------
    f32x4 acc[2][4] = {};
#pragma unroll
    for (int s = 0; s < 5; ++s) {
        bf16x8 af0 = *(const bf16x8*)(sA + (rowb + m) * KP + s * 32 + q * 8);
        bf16x8 af1 = *(const bf16x8*)(sA + (rowb + 16 + m) * KP + s * 32 + q * 8);
        bf16x8 bf[4];
#pragma unroll
        for (int n = 0; n < 4; ++n)
            bf[n] = *(const bf16x8*)(sW1 + (16 * n + m) * KP + s * 32 + q * 8);
#pragma unroll
        for (int n = 0; n < 4; ++n) {
            acc[0][n] = __builtin_amdgcn_mfma_f32_16x16x32_bf16(af0, bf[n], acc[0][n], 0, 0, 0);
            acc[1][n] = __builtin_amdgcn_mfma_f32_16x16x32_bf16(af1, bf[n], acc[1][n], 0, 0, 0);
        }
    }
    __syncthreads();                         // everyone done reading sA

    // silu(+b1) -> X1 bf16 [128][72] at smem base
    unsigned short* sX1 = (unsigned short*)smem;
#pragma unroll
    for (int tt = 0; tt < 2; ++tt)
#pragma unroll
        for (int n = 0; n < 4; ++n) {
            float bb = sB1[16 * n + m];
#pragma unroll
            for (int i = 0; i < 4; ++i) {
                float y = silu_f(acc[tt][n][i] + bb);
                sX1[(rowb + 16 * tt + 4 * q + i) * 72 + 16 * n + m] = f2bf(y);
            }
        }
    __syncthreads();

    // ---------- layer 2: [128,64] @ [64,64] ----------
    f32x4 acc2[2][4] = {};
#pragma unroll
    for (int s = 0; s < 2; ++s) {
        bf16x8 af0 = *(const bf16x8*)(sX1 + (rowb + m) * 72 + s * 32 + q * 8);
        bf16x8 af1 = *(const bf16x8*)(sX1 + (rowb + 16 + m) * 72 + s * 32 + q * 8);
        bf16x8 bf[4];
#pragma unroll
        for (int n = 0; n < 4; ++n)
            bf[n] = *(const bf16x8*)(sW2 + (16 * n + m) * 72 + s * 32 + q * 8);
#pragma unroll
        for (int n = 0; n < 4; ++n) {
            acc2[0][n] = __builtin_amdgcn_mfma_f32_16x16x32_bf16(af0, bf[n], acc2[0][n], 0, 0, 0);
            acc2[1][n] = __builtin_amdgcn_mfma_f32_16x16x32_bf16(af1, bf[n], acc2[1][n], 0, 0, 0);
        }
    }
    __syncthreads();                         // everyone done reading X1

    // silu(+b2) -> X2 f32 [128][66] at smem base
    float* sX2 = (float*)smem;
#pragma unroll
    for (int tt = 0; tt < 2; ++tt)
#pragma unroll
        for (int n = 0; n < 4; ++n) {
            float bb = sB2[16 * n + m];
#pragma unroll
            for (int i = 0; i < 4; ++i) {
                float y = silu_f(acc2[tt][n][i] + bb);
                sX2[(rowb + 16 * tt + 4 * q + i) * 66 + 16 * n + m] = y;
            }
        }
    __syncthreads();

    // ---------- epilogue: scal = X2 @ W3 ; coord-diff ; atomics ----------
    if (t < MT) {
        int e = e0 + t;
        if (e < E_) {
            const float* x2 = sX2 + t * 66;
            float s0 = 0.f, s1 = 0.f, s2 = 0.f, s3 = 0.f;
#pragma unroll
            for (int j = 0; j < HD; j += 4) {          // W3[j] wave-uniform -> s_load
                s0 = fmaf(x2[j + 0], W3[j + 0], s0);
                s1 = fmaf(x2[j + 1], W3[j + 1], s1);
                s2 = fmaf(x2[j + 2], W3[j + 2], s2);
                s3 = fmaf(x2[j + 3], W3[j + 3], s3);
            }
            float scal = ((s0 + s1) + (s2 + s3)) * NORM_INV;
            int r = eidx[e], c = eidx[(size_t)E_ + e];
            float cdx = coord[r * 3 + 0] - coord[c * 3 + 0];
            float cdy = coord[r * 3 + 1] - coord[c * 3 + 1];
            float cdz = coord[r * 3 + 2] - coord[c * 3 + 2];
            float radial = cdx * cdx + cdy * cdy + cdz * cdz;
            float inv = __builtin_amdgcn_rcpf(sqrtf(radial + 1e-8f) + 1.0f);
            float sc = scal * inv;
            atomicAdd(&out[r * 3 + 0], cdx * sc);
            atomicAdd(&out[r * 3 + 1], cdy * sc);
            atomicAdd(&out[r * 3 + 2], cdz * sc);
        }
    }
}

// ================= fallback (round-2 proven path, needs only 16 KB ws) =================
__global__ void prep_fb_kernel(const float* __restrict__ coord, float* __restrict__ out, int n3,
                               const float* __restrict__ W2, float* __restrict__ W2t) {
    int i = blockIdx.x * blockDim.x + threadIdx.x;
    if (i < n3) out[i] = coord[i];
    if (i < HD * HD) W2t[(i & 63) * HD + (i >> 6)] = W2[i];
}

__global__ __launch_bounds__(256, 4) void egnn_fb_kernel(
    const float* __restrict__ h, const float* __restrict__ coord,
    const int* __restrict__ eidx, const float* __restrict__ edge_attr,
    const float* __restrict__ W1, const float* __restrict__ b1,
    const float* __restrict__ W2t, const float* __restrict__ b2,
    const float* __restrict__ W3, float* __restrict__ out, int E_)
{
    int e = blockIdx.x * 256 + threadIdx.x;
    if (e >= E_) return;
    int row = eidx[e], col = eidx[E_ + e];
    const float4* hr = reinterpret_cast<const float4*>(h + (size_t)row * HD);
    const float4* hc = reinterpret_cast<const float4*>(h + (size_t)col * HD);
    const float4* ea = reinterpret_cast<const float4*>(edge_attr + (size_t)e * EIN);
    float4 ea0 = ea[0], ea1 = ea[1];
    float cdx = coord[row * 3 + 0] - coord[col * 3 + 0];
    float cdy = coord[row * 3 + 1] - coord[col * 3 + 1];
    float cdz = coord[row * 3 + 2] - coord[col * 3 + 2];
    float inv = __builtin_amdgcn_rcpf(sqrtf(cdx * cdx + cdy * cdy + cdz * cdz + 1e-8f) + 1.0f);
    cdx *= inv; cdy *= inv; cdz *= inv;
    float acc[HD];
#pragma unroll
    for (int j = 0; j < HD; ++j) acc[j] = b1[j];
    auto fma_row = [&](const float* __restrict__ wv, float a) {
#pragma unroll
        for (int j = 0; j < HD; ++j) acc[j] = fmaf(a, wv[j], acc[j]);
    };
    for (int kk = 0; kk < HD / 4; ++kk) {
        float4 av = hr[kk];
        fma_row(W1 + (4 * kk + 0) * HD, av.x); fma_row(W1 + (4 * kk + 1) * HD, av.y);
        fma_row(W1 + (4 * kk + 2) * HD, av.z); fma_row(W1 + (4 * kk + 3) * HD, av.w);
    }
    for (int kk = 0; kk < HD / 4; ++kk) {
        float4 av = hc[kk];
        fma_row(W1 + (HD + 4 * kk + 0) * HD, av.x); fma_row(W1 + (HD + 4 * kk + 1) * HD, av.y);
        fma_row(W1 + (HD + 4 * kk + 2) * HD, av.z); fma_row(W1 + (HD + 4 * kk + 3) * HD, av.w);
    }
    fma_row(W1 + 128 * HD, ea0.x); fma_row(W1 + 129 * HD, ea0.y);
    fma_row(W1 + 130 * HD, ea0.z); fma_row(W1 + 131 * HD, ea0.w);
    fma_row(W1 + 132 * HD, ea1.x); fma_row(W1 + 133 * HD, ea1.y);
    fma_row(W1 + 134 * HD, ea1.z); fma_row(W1 + 135 * HD, ea1.w);
#pragma unroll
    for (int j = 0; j < HD; ++j) acc[j] = silu_f(acc[j]);
    float scal = 0.0f;
    for (int j = 0; j < HD; ++j) {
        const float* wv = W2t + j * HD;
        float t0 = b2[j], t1 = 0.f, t2 = 0.f, t3 = 0.f;
#pragma unroll
        for (int k = 0; k < HD; k += 4) {
            t0 = fmaf(acc[k + 0], wv[k + 0], t0); t1 = fmaf(acc[k + 1], wv[k + 1], t1);
            t2 = fmaf(acc[k + 2], wv[k + 2], t2); t3 = fmaf(acc[k + 3], wv[k + 3], t3);
        }
        scal = fmaf(silu_f((t0 + t1) + (t2 + t3)), W3[j], scal);
    }
    float s = scal * NORM_INV;
    atomicAdd(&out[row * 3 + 0], cdx * s);
    atomicAdd(&out[row * 3 + 1], cdy * s);
    atomicAdd(&out[row * 3 + 2], cdz * s);
}

extern "C" void kernel_launch(void* const* d_in, const int* in_sizes, int n_in,
                              void* d_out, int out_size, void* d_ws, size_t ws_size,
                              hipStream_t stream) {
    const float* h         = (const float*)d_in[0];
    const float* coord     = (const float*)d_in[1];
    const int*   eidx      = (const int*)  d_in[2];
    const float* edge_attr = (const float*)d_in[3];
    const float* W1        = (const float*)d_in[4];
    const float* b1        = (const float*)d_in[5];
    const float* W2        = (const float*)d_in[6];
    const float* b2        = (const float*)d_in[7];
    const float* W3        = (const float*)d_in[8];
    float* out = (float*)d_out;

    int E_ = in_sizes[2] / 2;
    int n3 = out_size;
    int nf = in_sizes[0];            // N*HD floats of h

    if (ws_size >= WS_NEED(nf)) {
        unsigned short* hbf = (unsigned short*)d_ws;
        unsigned short* w1t = (unsigned short*)((char*)d_ws + W1T_OFF(nf));
        unsigned short* w2t = w1t + 64 * KP;
        int npairs = nf / 2;
        int pgrid = (npairs > n3 ? npairs : n3);
        hipLaunchKernelGGL(prep_h_kernel, dim3((pgrid + 255) / 256), dim3(256), 0, stream,
                           h, hbf, npairs, coord, out, n3);
        hipLaunchKernelGGL(prep_w_kernel, dim3(1), dim3(256), 0, stream, W1, W2, w1t, w2t);
        hipLaunchKernelGGL(egnn_mfma_kernel, dim3((E_ + MT - 1) / MT), dim3(256), 0, stream,
                           hbf, coord, eidx, edge_attr, w1t, w2t, b1, b2, W3, out, E_);
    } else {
        float* W2t = (float*)d_ws;   // 16 KB
        hipLaunchKernelGGL(prep_fb_kernel, dim3((n3 + 255) / 256), dim3(256), 0, stream,
                           coord, out, n3, W2, W2t);
        hipLaunchKernelGGL(egnn_fb_kernel, dim3((E_ + 255) / 256), dim3(256), 0, stream,
                           h, coord, eidx, edge_attr, W1, b1, W2t, b2, W3, out, E_);
    }
}

// Round 4
// 462.106 us; speedup vs baseline: 1.9904x; 1.9904x over previous
//
#include <hip/hip_runtime.h>
#include <math.h>

#define HD   64
#define EIN  8
#define MT   128          // edges per block
#define KP   160          // layer-1 K padded to 5*32
#define W2S  72           // layer-2 weight/X1 row stride (u16), pad for banks
#define NORM_INV 0.01f

typedef short bf16x8 __attribute__((ext_vector_type(8)));
typedef float f32x4  __attribute__((ext_vector_type(4)));

#define WS_W_BYTES ((size_t)(64 * KP + 64 * W2S) * 2)   // 29696

__device__ __forceinline__ unsigned short f2bf(float f) {
    union { float f; unsigned u; } v; v.f = f;
    unsigned r = v.u + 0x7FFFu + ((v.u >> 16) & 1u);
    return (unsigned short)(r >> 16);
}
__device__ __forceinline__ unsigned pk2(float a, float b) {
    return (unsigned)f2bf(a) | ((unsigned)f2bf(b) << 16);
}
__device__ __forceinline__ float silu_f(float x) {
    return x * __builtin_amdgcn_rcpf(1.0f + __expf(-x));
}

// ---- prep: coord -> out copy ----
__global__ void prep_out_kernel(const float* __restrict__ coord,
                                float* __restrict__ out, int n3) {
    int i = blockIdx.x * blockDim.x + threadIdx.x;
    if (i < n3) out[i] = coord[i];
}

// ---- prep: transposed bf16 weights into ws (one block; only if ws fits) ----
__global__ void prep_w_kernel(const float* __restrict__ W1, const float* __restrict__ W2,
                              unsigned short* __restrict__ w1t, unsigned short* __restrict__ w2t) {
    int t = threadIdx.x;
    for (int i = t; i < 64 * KP; i += 256) {
        int n = i / KP, k = i - n * KP;
        w1t[i] = (k < 136) ? f2bf(W1[k * HD + n]) : (unsigned short)0;
    }
    for (int i = t; i < 64 * W2S; i += 256) {
        int n = i / W2S, k = i - n * W2S;
        w2t[i] = (k < 64) ? f2bf(W2[k * HD + n]) : (unsigned short)0;
    }
}

// ---- main MFMA kernel ----
// LDS map (71168 B): sA [128][160]u16 stride 320B at 0 (later aliased by
// X1 [128][72]u16 and X2 [128][66]f32); sW1 [64][160]u16 at 40960;
// sW2 [64][72]u16 at 61440; b1 f32[64] at 70656; b2 f32[64] at 70912.
template <bool WSW>
__global__ __launch_bounds__(256, 2) void egnn_mfma_kernel(
    const float* __restrict__ h,          // fp32, converted on the fly
    const float* __restrict__ coord,
    const int*   __restrict__ eidx,
    const float* __restrict__ eattr,
    const float* __restrict__ W1f,        // fp32 weights (used when !WSW)
    const float* __restrict__ W2f,
    const unsigned short* __restrict__ w1t,  // bf16 pre-transposed (when WSW)
    const unsigned short* __restrict__ w2t,
    const float* __restrict__ b1,
    const float* __restrict__ b2,
    const float* __restrict__ W3,
    float* __restrict__ out,
    int E_)
{
    __shared__ char smem[71168];
    unsigned short* sA  = (unsigned short*)smem;
    unsigned short* sW1 = (unsigned short*)(smem + 40960);
    unsigned short* sW2 = (unsigned short*)(smem + 61440);
    float* sB1 = (float*)(smem + 70656);
    float* sB2 = (float*)(smem + 70912);

    const int t  = threadIdx.x;
    const int e0 = blockIdx.x * MT;

    // ---------- stage A tile: 2 threads per edge, fp32 h -> bf16 ----------
    {
        int el = t & (MT - 1), part = t >> 7;
        int e = e0 + el; if (e >= E_) e = E_ - 1;
        int node = (part == 0) ? eidx[e] : eidx[(size_t)E_ + e];
        const float4* src = (const float4*)(h + (size_t)node * HD);
        uint4* dst = (uint4*)(sA + el * KP + part * HD);  // 16B-aligned
#pragma unroll
        for (int i = 0; i < 8; ++i) {
            float4 a = src[2 * i], b = src[2 * i + 1];
            uint4 v;
            v.x = pk2(a.x, a.y); v.y = pk2(a.z, a.w);
            v.z = pk2(b.x, b.y); v.w = pk2(b.z, b.w);
            dst[i] = v;
        }
        uint4 z; z.x = z.y = z.z = z.w = 0;
        uint4* base = (uint4*)(sA + el * KP);
        if (part == 0) {                       // zero pad k = 144..159
            base[18] = z; base[19] = z;
        } else {                               // edge_attr k = 128..135; zero 136..143
            const float4* eap = (const float4*)(eattr + (size_t)e * EIN);
            float4 a0 = eap[0], a1 = eap[1];
            uint4 v;
            v.x = pk2(a0.x, a0.y); v.y = pk2(a0.z, a0.w);
            v.z = pk2(a1.x, a1.y); v.w = pk2(a1.z, a1.w);
            base[16] = v; base[17] = z;
        }
    }
    // ---------- stage weights + biases ----------
    if (WSW) {
        const uint4* s1 = (const uint4*)w1t; uint4* d1 = (uint4*)sW1;
        for (int i = t; i < (64 * KP) / 8; i += 256) d1[i] = s1[i];
        const uint4* s2 = (const uint4*)w2t; uint4* d2 = (uint4*)sW2;
        for (int i = t; i < (64 * W2S) / 8; i += 256) d2[i] = s2[i];
    } else {
        for (int i = t; i < 136 * 64; i += 256) {        // coalesced fp32 read, scattered b16 write
            int k = i >> 6, n = i & 63;
            sW1[n * KP + k] = f2bf(W1f[i]);
        }
        for (int i = t; i < 24 * 64; i += 256) {         // zero pad k = 136..159 (0*NaN guard)
            int n = i / 24, k = 136 + i - n * 24;
            sW1[n * KP + k] = 0;
        }
        for (int i = t; i < 64 * 64; i += 256) {
            int k = i >> 6, n = i & 63;
            sW2[n * W2S + k] = f2bf(W2f[i]);
        }
    }
    if (t < 64) sB1[t] = b1[t];
    else if (t < 128) sB2[t - 64] = b2[t - 64];
    __syncthreads();

    const int w = t >> 6, lane = t & 63;
    const int m = lane & 15, q = lane >> 4;
    const int rowb = 32 * w;                 // this wave owns edge-rows rowb..rowb+31

    // ---------- layer 1: [128,160] @ [160,64] ----------
    f32x4 acc[2][4] = {};
#pragma unroll
    for (int s = 0; s < 5; ++s) {
        bf16x8 af0 = *(const bf16x8*)(sA + (rowb + m) * KP + s * 32 + q * 8);
        bf16x8 af1 = *(const bf16x8*)(sA + (rowb + 16 + m) * KP + s * 32 + q * 8);
        bf16x8 bf[4];
#pragma unroll
        for (int n = 0; n < 4; ++n)
            bf[n] = *(const bf16x8*)(sW1 + (16 * n + m) * KP + s * 32 + q * 8);
#pragma unroll
        for (int n = 0; n < 4; ++n) {
            acc[0][n] = __builtin_amdgcn_mfma_f32_16x16x32_bf16(af0, bf[n], acc[0][n], 0, 0, 0);
            acc[1][n] = __builtin_amdgcn_mfma_f32_16x16x32_bf16(af1, bf[n], acc[1][n], 0, 0, 0);
        }
    }
    __syncthreads();                         // everyone done reading sA

    // silu(+b1) -> X1 bf16 [128][72] at smem base
    unsigned short* sX1 = (unsigned short*)smem;
#pragma unroll
    for (int tt = 0; tt < 2; ++tt)
#pragma unroll
        for (int n = 0; n < 4; ++n) {
            float bb = sB1[16 * n + m];
#pragma unroll
            for (int i = 0; i < 4; ++i) {
                float y = silu_f(acc[tt][n][i] + bb);
                sX1[(rowb + 16 * tt + 4 * q + i) * W2S + 16 * n + m] = f2bf(y);
            }
        }
    __syncthreads();

    // ---------- layer 2: [128,64] @ [64,64] ----------
    f32x4 acc2[2][4] = {};
#pragma unroll
    for (int s = 0; s < 2; ++s) {
        bf16x8 af0 = *(const bf16x8*)(sX1 + (rowb + m) * W2S + s * 32 + q * 8);
        bf16x8 af1 = *(const bf16x8*)(sX1 + (rowb + 16 + m) * W2S + s * 32 + q * 8);
        bf16x8 bf[4];
#pragma unroll
        for (int n = 0; n < 4; ++n)
            bf[n] = *(const bf16x8*)(sW2 + (16 * n + m) * W2S + s * 32 + q * 8);
#pragma unroll
        for (int n = 0; n < 4; ++n) {
            acc2[0][n] = __builtin_amdgcn_mfma_f32_16x16x32_bf16(af0, bf[n], acc2[0][n], 0, 0, 0);
            acc2[1][n] = __builtin_amdgcn_mfma_f32_16x16x32_bf16(af1, bf[n], acc2[1][n], 0, 0, 0);
        }
    }
    __syncthreads();                         // everyone done reading X1

    // silu(+b2) -> X2 f32 [128][66] at smem base
    float* sX2 = (float*)smem;
#pragma unroll
    for (int tt = 0; tt < 2; ++tt)
#pragma unroll
        for (int n = 0; n < 4; ++n) {
            float bb = sB2[16 * n + m];
#pragma unroll
            for (int i = 0; i < 4; ++i) {
                float y = silu_f(acc2[tt][n][i] + bb);
                sX2[(rowb + 16 * tt + 4 * q + i) * 66 + 16 * n + m] = y;
            }
        }
    __syncthreads();

    // ---------- epilogue: scal = X2 @ W3 ; coord-diff ; atomics ----------
    if (t < MT) {
        int e = e0 + t;
        if (e < E_) {
            const float* x2 = sX2 + t * 66;
            float s0 = 0.f, s1 = 0.f, s2 = 0.f, s3 = 0.f;
#pragma unroll
            for (int j = 0; j < HD; j += 4) {          // W3 wave-uniform -> s_load
                s0 = fmaf(x2[j + 0], W3[j + 0], s0);
                s1 = fmaf(x2[j + 1], W3[j + 1], s1);
                s2 = fmaf(x2[j + 2], W3[j + 2], s2);
                s3 = fmaf(x2[j + 3], W3[j + 3], s3);
            }
            float scal = ((s0 + s1) + (s2 + s3)) * NORM_INV;
            int r = eidx[e], c = eidx[(size_t)E_ + e];
            float cdx = coord[r * 3 + 0] - coord[c * 3 + 0];
            float cdy = coord[r * 3 + 1] - coord[c * 3 + 1];
            float cdz = coord[r * 3 + 2] - coord[c * 3 + 2];
            float radial = cdx * cdx + cdy * cdy + cdz * cdz;
            float inv = __builtin_amdgcn_rcpf(sqrtf(radial + 1e-8f) + 1.0f);
            float sc = scal * inv;
            atomicAdd(&out[r * 3 + 0], cdx * sc);
            atomicAdd(&out[r * 3 + 1], cdy * sc);
            atomicAdd(&out[r * 3 + 2], cdz * sc);
        }
    }
}

extern "C" void kernel_launch(void* const* d_in, const int* in_sizes, int n_in,
                              void* d_out, int out_size, void* d_ws, size_t ws_size,
                              hipStream_t stream) {
    const float* h         = (const float*)d_in[0];
    const float* coord     = (const float*)d_in[1];
    const int*   eidx      = (const int*)  d_in[2];
    const float* edge_attr = (const float*)d_in[3];
    const float* W1        = (const float*)d_in[4];
    const float* b1        = (const float*)d_in[5];
    const float* W2        = (const float*)d_in[6];
    const float* b2        = (const float*)d_in[7];
    const float* W3        = (const float*)d_in[8];
    float* out = (float*)d_out;

    int E_ = in_sizes[2] / 2;    // edge_index is [2, E]
    int n3 = out_size;           // N*3
    int nblk = (E_ + MT - 1) / MT;

    hipLaunchKernelGGL(prep_out_kernel, dim3((n3 + 255) / 256), dim3(256), 0, stream,
                       coord, out, n3);

    if (ws_size >= WS_W_BYTES) {
        unsigned short* w1t = (unsigned short*)d_ws;
        unsigned short* w2t = w1t + 64 * KP;
        hipLaunchKernelGGL(prep_w_kernel, dim3(1), dim3(256), 0, stream, W1, W2, w1t, w2t);
        hipLaunchKernelGGL((egnn_mfma_kernel<true>), dim3(nblk), dim3(256), 0, stream,
                           h, coord, eidx, edge_attr, W1, W2, w1t, w2t, b1, b2, W3, out, E_);
    } else {
        hipLaunchKernelGGL((egnn_mfma_kernel<false>), dim3(nblk), dim3(256), 0, stream,
                           h, coord, eidx, edge_attr, W1, W2,
                           (const unsigned short*)nullptr, (const unsigned short*)nullptr,
                           b1, b2, W3, out, E_);
    }
}

// Round 5
// 419.640 us; speedup vs baseline: 2.1918x; 1.1012x over previous
//
#include <hip/hip_runtime.h>
#include <math.h>

#define HD   64
#define EIN  8
#define SAS  168          // sA row stride in u16 (336 B): 20*m mod 32 -> conflict-free
#define W2S  72           // sW2 row stride in u16 (144 B): 4*m mod 32 -> 2-way (free)
#define X1OFF 96          // X1[e] lives at sA row byte offset 192 (u16 96..167)
#define NORM_INV 0.01f

typedef short bf16x8 __attribute__((ext_vector_type(8)));
typedef float f32x4  __attribute__((ext_vector_type(4)));

__device__ __forceinline__ unsigned short f2bf(float f) {
    union { float f; unsigned u; } v; v.f = f;
    unsigned r = v.u + 0x7FFFu + ((v.u >> 16) & 1u);
    return (unsigned short)(r >> 16);
}
__device__ __forceinline__ unsigned pk2(float a, float b) {
    return (unsigned)f2bf(a) | ((unsigned)f2bf(b) << 16);
}
__device__ __forceinline__ float silu_f(float x) {
    return x * __builtin_amdgcn_rcpf(1.0f + __expf(-x));
}

__global__ void prep_out_kernel(const float* __restrict__ coord,
                                float* __restrict__ out, int n3) {
    int i = blockIdx.x * blockDim.x + threadIdx.x;
    if (i < n3) out[i] = coord[i];
}

// One persistent-ish kernel: weights->LDS once per block, then a grid-stride
// loop over 16-edge groups. Each WAVE owns its groups end-to-end: staging,
// both MFMA layers, epilogue. All sharing is intra-wave => NO barriers in the
// steady-state loop. Operand-swapped MFMA (A=weights, B=edges) makes X1 a
// packed b64 write and keeps the final dot in registers.
__global__ __launch_bounds__(256, 3) void egnn_mfma_kernel(
    const float* __restrict__ h,
    const float* __restrict__ coord,
    const int*   __restrict__ eidx,
    const float* __restrict__ eattr,
    const float* __restrict__ W1f,    // [136][64] fp32
    const float* __restrict__ W2f,    // [64][64] fp32
    const float* __restrict__ b1,
    const float* __restrict__ b2,
    const float* __restrict__ W3,
    float* __restrict__ out,
    int E_)
{
    __shared__ unsigned short sW1[64 * SAS];   // [n][k], k-contig, stride 168
    __shared__ unsigned short sW2[64 * W2S];   // [n][k], k-contig, stride 72
    __shared__ float sB1[64], sB2[64], sW3[64];
    __shared__ unsigned short sA[64 * SAS];    // 4 waves x 16 edge rows

    const int t = threadIdx.x;

    // ---- weights -> LDS (once per block; coalesced fp32 read, bf16 scatter) ----
    for (int i = t; i < 136 * 64; i += 256) {
        int k = i >> 6, n = i & 63;
        sW1[n * SAS + k] = f2bf(W1f[i]);
    }
    for (int i = t; i < 24 * 64; i += 256) {   // zero-pad k=136..159 (NaN guard)
        int n = i / 24, k = 136 + (i - n * 24);
        sW1[n * SAS + k] = 0;
    }
    for (int i = t; i < 64 * 64; i += 256) {
        int k = i >> 6, n = i & 63;
        sW2[n * W2S + k] = f2bf(W2f[i]);
    }
    if (t < 64) sB1[t] = b1[t];
    else if (t < 128) sB2[t - 64] = b2[t - 64];
    else if (t < 192) sW3[t - 128] = W3[t - 128];
    __syncthreads();                            // the ONLY barrier

    const int w = t >> 6, lane = t & 63;
    const int m = lane & 15, q = lane >> 4;
    const int sm = lane >> 2, sp = lane & 3;    // staging: 4 threads per edge

    unsigned short* stageRow = sA + (16 * w + sm) * SAS;  // row this thread stages
    unsigned short* fragRow  = sA + (16 * w + m) * SAS;   // row this lane reads (edge=m)

    // per-lane bias/W3 fragments (lane-invariant across tiles)
    float4 b1v[4], b2v[4], w3v[4];
#pragma unroll
    for (int nt = 0; nt < 4; ++nt) {
        b1v[nt] = *(const float4*)(&sB1[16 * nt + 4 * q]);
        b2v[nt] = *(const float4*)(&sB2[16 * nt + 4 * q]);
        w3v[nt] = *(const float4*)(&sW3[16 * nt + 4 * q]);
    }

    const int ngroups = (E_ + 15) >> 4;
    for (int g = blockIdx.x * 4 + w; g < ngroups; g += gridDim.x * 4) {
        const int ebase = g * 16;

        // ---------- stage 16 edges (this wave's rows only) ----------
        {
            int e = ebase + sm;
            int ec = (e < E_) ? e : (E_ - 1);
            int node = (sp < 2) ? eidx[ec] : eidx[(size_t)E_ + ec];
            const float4* src = (const float4*)(h + (size_t)node * HD) + (sp & 1) * 8;
            uint4* dst = (uint4*)stageRow + sp * 4;       // k in [32*sp, 32*sp+32)
#pragma unroll
            for (int i = 0; i < 4; ++i) {
                float4 a = src[2 * i], b = src[2 * i + 1];
                uint4 v;
                v.x = pk2(a.x, a.y); v.y = pk2(a.z, a.w);
                v.z = pk2(b.x, b.y); v.w = pk2(b.z, b.w);
                dst[i] = v;
            }
            if (sp == 3) {                                // edge_attr k=128..135 + zero pad
                const float4* eap = (const float4*)(eattr + (size_t)ec * EIN);
                float4 a0 = eap[0], a1 = eap[1];
                uint4 v;
                v.x = pk2(a0.x, a0.y); v.y = pk2(a0.z, a0.w);
                v.z = pk2(a1.x, a1.y); v.w = pk2(a1.z, a1.w);
                *((uint4*)(stageRow + 128)) = v;
                uint4 z; z.x = z.y = z.z = z.w = 0;
                *((uint4*)(stageRow + 136)) = z;
                *((uint4*)(stageRow + 144)) = z;
                *((uint4*)(stageRow + 152)) = z;
            }
        }
        // no barrier: this wave wrote these rows, this wave reads them (lgkmcnt)

        // ---------- layer 1: D1[n2][e] = sum_k W1t[n2][k] * inp[e][k] ----------
        f32x4 acc1[4] = {};
#pragma unroll
        for (int s = 0; s < 5; ++s) {
            bf16x8 bfrag = *(const bf16x8*)(fragRow + s * 32 + q * 8);
#pragma unroll
            for (int nt = 0; nt < 4; ++nt) {
                bf16x8 afrag = *(const bf16x8*)(sW1 + (16 * nt + m) * SAS + s * 32 + q * 8);
                acc1[nt] = __builtin_amdgcn_mfma_f32_16x16x32_bf16(afrag, bfrag, acc1[nt], 0, 0, 0);
            }
        }

        // silu -> X1[e][k] packed b64 (4 consecutive k per lane), aliased into
        // this wave's own sA rows at byte offset 192 (k96..167 region, post-read)
        unsigned short* x1Row = fragRow + X1OFF;
#pragma unroll
        for (int nt = 0; nt < 4; ++nt) {
            ushort4 pk;
            pk.x = f2bf(silu_f(acc1[nt][0] + b1v[nt].x));
            pk.y = f2bf(silu_f(acc1[nt][1] + b1v[nt].y));
            pk.z = f2bf(silu_f(acc1[nt][2] + b1v[nt].z));
            pk.w = f2bf(silu_f(acc1[nt][3] + b1v[nt].w));
            *((ushort4*)(x1Row + 16 * nt + 4 * q)) = pk;
        }

        // ---------- layer 2: D2[n2][e] = sum_k W2t[n2][k] * X1[e][k] ----------
        f32x4 acc2[4] = {};
#pragma unroll
        for (int s = 0; s < 2; ++s) {
            bf16x8 bfrag = *(const bf16x8*)(x1Row + s * 32 + q * 8);
#pragma unroll
            for (int nt = 0; nt < 4; ++nt) {
                bf16x8 afrag = *(const bf16x8*)(sW2 + (16 * nt + m) * W2S + s * 32 + q * 8);
                acc2[nt] = __builtin_amdgcn_mfma_f32_16x16x32_bf16(afrag, bfrag, acc2[nt], 0, 0, 0);
            }
        }

        // ---------- epilogue: scal = silu(X2) . W3, in registers ----------
        float p = 0.f;
#pragma unroll
        for (int nt = 0; nt < 4; ++nt) {
            p = fmaf(silu_f(acc2[nt][0] + b2v[nt].x), w3v[nt].x, p);
            p = fmaf(silu_f(acc2[nt][1] + b2v[nt].y), w3v[nt].y, p);
            p = fmaf(silu_f(acc2[nt][2] + b2v[nt].z), w3v[nt].z, p);
            p = fmaf(silu_f(acc2[nt][3] + b2v[nt].w), w3v[nt].w, p);
        }
        p += __shfl_xor(p, 16);   // butterfly over q-groups: all lanes get full dot
        p += __shfl_xor(p, 32);

        int e2 = ebase + m;
        if (e2 < E_ && q < 3) {                 // lanes q=0,1,2 handle x,y,z
            int r = eidx[e2], c = eidx[(size_t)E_ + e2];
            float cdx = coord[r * 3 + 0] - coord[c * 3 + 0];
            float cdy = coord[r * 3 + 1] - coord[c * 3 + 1];
            float cdz = coord[r * 3 + 2] - coord[c * 3 + 2];
            float radial = cdx * cdx + cdy * cdy + cdz * cdz;
            float inv = __builtin_amdgcn_rcpf(sqrtf(radial + 1e-8f) + 1.0f);
            float sc = p * NORM_INV * inv;
            float comp = (q == 0) ? cdx : ((q == 1) ? cdy : cdz);
            atomicAdd(&out[r * 3 + q], comp * sc);
        }
    }
}

extern "C" void kernel_launch(void* const* d_in, const int* in_sizes, int n_in,
                              void* d_out, int out_size, void* d_ws, size_t ws_size,
                              hipStream_t stream) {
    const float* h         = (const float*)d_in[0];
    const float* coord     = (const float*)d_in[1];
    const int*   eidx      = (const int*)  d_in[2];
    const float* edge_attr = (const float*)d_in[3];
    const float* W1        = (const float*)d_in[4];
    const float* b1        = (const float*)d_in[5];
    const float* W2        = (const float*)d_in[6];
    const float* b2        = (const float*)d_in[7];
    const float* W3        = (const float*)d_in[8];
    float* out = (float*)d_out;

    int E_ = in_sizes[2] / 2;    // edge_index is [2, E]
    int n3 = out_size;           // N*3

    hipLaunchKernelGGL(prep_out_kernel, dim3((n3 + 255) / 256), dim3(256), 0, stream,
                       coord, out, n3);

    // 768 blocks = 3 blocks/CU x 256 CUs; grid-stride over 16-edge groups
    hipLaunchKernelGGL(egnn_mfma_kernel, dim3(768), dim3(256), 0, stream,
                       h, coord, eidx, edge_attr, W1, W2, b1, b2, W3, out, E_);
}